// Round 1
// 636.833 us; speedup vs baseline: 1.1527x; 1.1527x over previous
//
#include <hip/hip_runtime.h>

#define NUM_USER  200000
#define NUM_GROUP 50000
#define NN        (NUM_USER + NUM_GROUP)   // 250000
#define E_EDGES   4000000
#define D         64
#define B         8192

#define SCAN_CHUNK   1024                                   // counts per block
#define SCAN_BLOCKS  ((NN + SCAN_CHUNK - 1) / SCAN_CHUNK)   // 245

#define BSHIFT       10                                     // 1024 rows / bucket
#define NB_BUCKETS   ((NN + (1 << BSHIFT) - 1) >> BSHIFT)   // 245
#define CHUNK_EDGES  4096                                   // edges per phase-A block
#define PB_THREADS   1024                                   // phase-B block size

// --- bf16 helpers (RNE; values are normal floats, no NaN path needed) ------
__device__ __forceinline__ float bf2f(unsigned short u) {
    return __uint_as_float(((unsigned int)u) << 16);
}
__device__ __forceinline__ unsigned short f2bf(float f) {
    unsigned int x = __float_as_uint(f);
    return (unsigned short)((x + 0x7FFFu + ((x >> 16) & 1u)) >> 16);
}
// packed-bf16 dword -> two floats (lo = even dim, hi = odd dim)
__device__ __forceinline__ float bflo(unsigned int u) { return __uint_as_float(u << 16); }
__device__ __forceinline__ float bfhi(unsigned int u) { return __uint_as_float(u & 0xFFFF0000u); }

// ---------------------------------------------------------------------------
// Convert concat(user_table, group_table) fp32 -> bf16 emb0 (vectorized x4)
// ---------------------------------------------------------------------------
__global__ void __launch_bounds__(256)
convert_tables(const float* __restrict__ ut,
               const float* __restrict__ gt,
               unsigned short* __restrict__ embT) {
    const long long total4 = (long long)NN * D / 4;
    const long long user4  = (long long)NUM_USER * D / 4;
    long long i = (long long)blockIdx.x * blockDim.x + threadIdx.x;
    if (i >= total4) return;
    float4 v = (i < user4) ? ((const float4*)ut)[i] : ((const float4*)gt)[i - user4];
    ushort4 o;
    o.x = f2bf(v.x); o.y = f2bf(v.y); o.z = f2bf(v.z); o.w = f2bf(v.w);
    ((ushort4*)embT)[i] = o;
}

// ---------------------------------------------------------------------------
// CSR build step 1: histogram of destination rows
// ---------------------------------------------------------------------------
__global__ void __launch_bounds__(256)
hist_kernel(const int* __restrict__ rows, int* __restrict__ counts) {
    int e = blockIdx.x * blockDim.x + threadIdx.x;
    if (e >= E_EDGES) return;
    atomicAdd(&counts[rows[e]], 1);
}

// ---------------------------------------------------------------------------
// Scan pass A: per-block sums of 1024 counts each
// ---------------------------------------------------------------------------
__global__ void __launch_bounds__(256)
scan_blocksums(const int* __restrict__ counts, int* __restrict__ blockSums) {
    __shared__ int red[256];
    const int t = threadIdx.x;
    const int base = blockIdx.x * SCAN_CHUNK + t * 4;
    int s = 0;
    #pragma unroll
    for (int k = 0; k < 4; ++k) {
        int i = base + k;
        if (i < NN) s += counts[i];
    }
    red[t] = s;
    __syncthreads();
    for (int off = 128; off > 0; off >>= 1) {
        if (t < off) red[t] += red[t + off];
        __syncthreads();
    }
    if (t == 0) blockSums[blockIdx.x] = red[0];
}

// ---------------------------------------------------------------------------
// Scan pass B: exclusive scan of the 245 block sums (single small block)
// ---------------------------------------------------------------------------
__global__ void __launch_bounds__(256)
scan_offsets(const int* __restrict__ blockSums,
             int* __restrict__ blockOffs,
             int* __restrict__ row_ptr) {
    __shared__ int s[256];
    const int t = threadIdx.x;
    int v = (t < SCAN_BLOCKS) ? blockSums[t] : 0;
    s[t] = v;
    __syncthreads();
    for (int off = 1; off < 256; off <<= 1) {
        int u = (t >= off) ? s[t - off] : 0;
        __syncthreads();
        s[t] += u;
        __syncthreads();
    }
    if (t < SCAN_BLOCKS) blockOffs[t] = s[t] - v;   // exclusive
    if (t == 255) row_ptr[NN] = s[255];             // grand total = E
}

// ---------------------------------------------------------------------------
// Scan pass C: intra-block exclusive scan + global offset -> row_ptr
// ---------------------------------------------------------------------------
__global__ void __launch_bounds__(256)
scan_final(const int* __restrict__ counts,
           const int* __restrict__ blockOffs,
           int* __restrict__ row_ptr) {
    __shared__ int s[256];
    const int t = threadIdx.x;
    const int base = blockIdx.x * SCAN_CHUNK + t * 4;
    int c0 = 0, c1 = 0, c2 = 0, c3 = 0;
    if (base + 0 < NN) c0 = counts[base + 0];
    if (base + 1 < NN) c1 = counts[base + 1];
    if (base + 2 < NN) c2 = counts[base + 2];
    if (base + 3 < NN) c3 = counts[base + 3];
    int tsum = c0 + c1 + c2 + c3;
    s[t] = tsum;
    __syncthreads();
    for (int off = 1; off < 256; off <<= 1) {
        int u = (t >= off) ? s[t - off] : 0;
        __syncthreads();
        s[t] += u;
        __syncthreads();
    }
    int run = blockOffs[blockIdx.x] + s[t] - tsum;   // exclusive prefix
    int p0 = run;
    int p1 = p0 + c0;
    int p2 = p1 + c1;
    int p3 = p2 + c2;
    if (base + 0 < NN) row_ptr[base + 0] = p0;
    if (base + 1 < NN) row_ptr[base + 1] = p1;
    if (base + 2 < NN) row_ptr[base + 2] = p2;
    if (base + 3 < NN) row_ptr[base + 3] = p3;
}

// ---------------------------------------------------------------------------
// Bucket cursors for phase A: staging region base = CSR base of the bucket
// ---------------------------------------------------------------------------
__global__ void __launch_bounds__(256)
init_bucket_cursors(const int* __restrict__ row_ptr, int* __restrict__ cursorA) {
    int b = blockIdx.x * blockDim.x + threadIdx.x;
    if (b < NB_BUCKETS) cursorA[b] = row_ptr[b << BSHIFT];
}

// ---------------------------------------------------------------------------
// Phase A: LDS-aggregated bucket append (parallel cursor reservation,
// 16-lane subgroup copy-out).
// Staged element: { (row_in_bucket << 18) | col, bits(val) }.
// ---------------------------------------------------------------------------
__global__ void __launch_bounds__(256)
bucket_phaseA(const int*   __restrict__ rows,
              const int*   __restrict__ cols,
              const float* __restrict__ vals,
              int*         __restrict__ cursorA,
              int2*        __restrict__ stage) {
    __shared__ int  cnt[256];
    __shared__ int  off[256];
    __shared__ int  cur[256];
    __shared__ int  gbase[256];
    __shared__ int2 stg[CHUNK_EDGES];    // 32 KB
    const int t = threadIdx.x;
    cnt[t] = 0;
    __syncthreads();

    const int base = blockIdx.x * CHUNK_EDGES;
    int re[CHUNK_EDGES / 256];           // cache rows -> no second global read
    #pragma unroll
    for (int k = 0; k < CHUNK_EDGES / 256; ++k) {
        int e = base + t + k * 256;
        re[k] = (e < E_EDGES) ? rows[e] : -1;
        if (re[k] >= 0) atomicAdd(&cnt[re[k] >> BSHIFT], 1);
    }
    __syncthreads();

    // exclusive scan of cnt -> off (Hillis-Steele over 256)
    int v = cnt[t];
    off[t] = v;
    __syncthreads();
    for (int o = 1; o < 256; o <<= 1) {
        int u = (t >= o) ? off[t - o] : 0;
        __syncthreads();
        off[t] += u;
        __syncthreads();
    }
    int excl = off[t] - v;
    __syncthreads();
    off[t] = excl;
    cur[t] = excl;
    // parallel cursor reservation: one independent atomic per bucket
    if (t < NB_BUCKETS && v > 0) gbase[t] = atomicAdd(&cursorA[t], v);
    __syncthreads();

    // place into LDS staging
    #pragma unroll
    for (int k = 0; k < CHUNK_EDGES / 256; ++k) {
        int r = re[k];
        if (r >= 0) {
            int e = base + t + k * 256;
            int b = r >> BSHIFT;
            int slot = atomicAdd(&cur[b], 1);
            stg[slot] = make_int2(((r & ((1 << BSHIFT) - 1)) << 18) | cols[e],
                                  __float_as_int(vals[e]));
        }
    }
    __syncthreads();

    // copy runs out: 16-lane subgroups (mean run length ~17), no atomics here
    const int sg = t >> 4;    // 0..15
    const int sl = t & 15;
    for (int b = sg; b < NB_BUCKETS; b += 16) {
        int n = cnt[b];
        if (n == 0) continue;
        int gb = gbase[b];
        int lb = off[b];
        for (int i = sl; i < n; i += 16)
            stage[gb + i] = stg[lb + i];
    }
}

// ---------------------------------------------------------------------------
// Phase B: exact CSR placement, ONE block per bucket. LDS cursors per row.
// 1024 threads/block: 245 blocks -> ~1 block/CU, 16 waves resident for
// latency hiding of the scattered 8B writes.
// ---------------------------------------------------------------------------
__global__ void __launch_bounds__(PB_THREADS)
bucket_phaseB(const int*  __restrict__ row_ptr,
              const int2* __restrict__ stage,
              int2*       __restrict__ pairs) {
    __shared__ int curs[1 << BSHIFT];    // 1024 row cursors
    const int b = blockIdx.x;
    const int rowBase = b << BSHIFT;
    const int nRows = (NN - rowBase < (1 << BSHIFT)) ? (NN - rowBase) : (1 << BSHIFT);
    const int t = threadIdx.x;
    for (int i = t; i < nRows; i += PB_THREADS) curs[i] = row_ptr[rowBase + i];
    __syncthreads();
    const int s = row_ptr[rowBase];
    const int e = row_ptr[(rowBase + (1 << BSHIFT) < NN) ? rowBase + (1 << BSHIFT) : NN];
    for (int i = s + t; i < e; i += PB_THREADS) {
        int2 p = stage[i];
        int rib = p.x >> 18;
        int col = p.x & 0x3FFFF;
        int slot = atomicAdd(&curs[rib], 1);
        pairs[slot] = make_int2(col, p.y);
    }
}

// ---------------------------------------------------------------------------
// Pull-mode SpMM over bf16 embeddings: one wave per destination row.
// Quarter-wave edge parallelism: 4 edges in flight, each handled by a
// 16-lane quarter; lane covers 4 dims via one 8-byte uint2 load.
// Unroll x2 -> 8 edges / 4 vmem instructions per wave-iteration.
// Cross-quarter reduction: 2x shfl_xor per row. fp32 acc, bf16 store.
// ---------------------------------------------------------------------------
__global__ void __launch_bounds__(256)
spmm_pull_bf(const int*  __restrict__ row_ptr,
             const int2* __restrict__ pairs,
             const unsigned short* __restrict__ x,
             unsigned short*       __restrict__ y) {
    const int row  = blockIdx.x * 4 + (threadIdx.x >> 6);   // 4 waves / block
    if (row >= NN) return;
    const int lane = threadIdx.x & 63;
    const int sub  = lane >> 4;          // quarter id 0..3 (edge slot)
    const int sl   = lane & 15;          // dims 4*sl .. 4*sl+3
    const int start = row_ptr[row];
    const int end   = row_ptr[row + 1];

    float a0 = 0.f, a1 = 0.f, a2 = 0.f, a3 = 0.f;
    int e = start + sub;                 // this quarter's edge ptr, stride 4
    for (; e + 4 < end; e += 8) {
        int2 p0 = pairs[e];
        int2 p1 = pairs[e + 4];
        uint2 u0 = *(const uint2*)(x + (unsigned)(p0.x * D + 4 * sl));
        uint2 u1 = *(const uint2*)(x + (unsigned)(p1.x * D + 4 * sl));
        float v0 = __int_as_float(p0.y);
        float v1 = __int_as_float(p1.y);
        a0 += v0 * bflo(u0.x); a1 += v0 * bfhi(u0.x);
        a2 += v0 * bflo(u0.y); a3 += v0 * bfhi(u0.y);
        a0 += v1 * bflo(u1.x); a1 += v1 * bfhi(u1.x);
        a2 += v1 * bflo(u1.y); a3 += v1 * bfhi(u1.y);
    }
    if (e < end) {                       // <=1 remaining edge per quarter
        int2 p = pairs[e];
        uint2 u = *(const uint2*)(x + (unsigned)(p.x * D + 4 * sl));
        float v = __int_as_float(p.y);
        a0 += v * bflo(u.x); a1 += v * bfhi(u.x);
        a2 += v * bflo(u.y); a3 += v * bfhi(u.y);
    }
    // combine the 4 quarters (same dims live at same sl in every quarter)
    a0 += __shfl_xor(a0, 16); a0 += __shfl_xor(a0, 32);
    a1 += __shfl_xor(a1, 16); a1 += __shfl_xor(a1, 32);
    a2 += __shfl_xor(a2, 16); a2 += __shfl_xor(a2, 32);
    a3 += __shfl_xor(a3, 16); a3 += __shfl_xor(a3, 32);
    if (sub == 0) {
        ushort4 o;
        o.x = f2bf(a0); o.y = f2bf(a1); o.z = f2bf(a2); o.w = f2bf(a3);
        *(ushort4*)(y + (unsigned)(row * D + 4 * sl)) = o;
    }
}

// ---------------------------------------------------------------------------
// Final level, output-sparse: one wave per OUTPUT SLOT (3*B slots), same
// quarter-wave structure as spmm_pull_bf; adds 0.25*sum into d_out.
// ---------------------------------------------------------------------------
__global__ void __launch_bounds__(256)
final_pull(const int*  __restrict__ row_ptr,
           const int2* __restrict__ pairs,
           const unsigned short* __restrict__ x,      // emb2 bf16
           const int*  __restrict__ ui,
           const int*  __restrict__ pg,
           const int*  __restrict__ ng,
           float*      __restrict__ out) {
    const int slot = blockIdx.x * 4 + (threadIdx.x >> 6);   // 0 .. 3*B-1
    if (slot >= 3 * B) return;
    const int lane = threadIdx.x & 63;
    const int sub  = lane >> 4;
    const int sl   = lane & 15;
    const int region = slot / B;                 // 0=user, 1=pos, 2=neg
    const int b      = slot - region * B;
    int row;
    if (region == 0)      row = ui[b];
    else if (region == 1) row = NUM_USER + pg[b];
    else                  row = NUM_USER + ng[b];

    const int start = row_ptr[row];
    const int end   = row_ptr[row + 1];
    float a0 = 0.f, a1 = 0.f, a2 = 0.f, a3 = 0.f;
    int e = start + sub;
    for (; e + 4 < end; e += 8) {
        int2 p0 = pairs[e];
        int2 p1 = pairs[e + 4];
        uint2 u0 = *(const uint2*)(x + (unsigned)(p0.x * D + 4 * sl));
        uint2 u1 = *(const uint2*)(x + (unsigned)(p1.x * D + 4 * sl));
        float v0 = __int_as_float(p0.y);
        float v1 = __int_as_float(p1.y);
        a0 += v0 * bflo(u0.x); a1 += v0 * bfhi(u0.x);
        a2 += v0 * bflo(u0.y); a3 += v0 * bfhi(u0.y);
        a0 += v1 * bflo(u1.x); a1 += v1 * bfhi(u1.x);
        a2 += v1 * bflo(u1.y); a3 += v1 * bfhi(u1.y);
    }
    if (e < end) {
        int2 p = pairs[e];
        uint2 u = *(const uint2*)(x + (unsigned)(p.x * D + 4 * sl));
        float v = __int_as_float(p.y);
        a0 += v * bflo(u.x); a1 += v * bfhi(u.x);
        a2 += v * bflo(u.y); a3 += v * bfhi(u.y);
    }
    a0 += __shfl_xor(a0, 16); a0 += __shfl_xor(a0, 32);
    a1 += __shfl_xor(a1, 16); a1 += __shfl_xor(a1, 32);
    a2 += __shfl_xor(a2, 16); a2 += __shfl_xor(a2, 32);
    a3 += __shfl_xor(a3, 16); a3 += __shfl_xor(a3, 32);
    if (sub == 0) {
        float* o = out + (unsigned)(region * B * D + b * D + 4 * sl);
        float4 t = *(float4*)o;
        t.x += 0.25f * a0; t.y += 0.25f * a1;
        t.z += 0.25f * a2; t.w += 0.25f * a3;
        *(float4*)o = t;
    }
}

// ---------------------------------------------------------------------------
// Output init: raw table gathers (outputs 3..5, exact fp32) and the level-0
// contribution (0.25 * table rows) into outputs 0..2.
// ---------------------------------------------------------------------------
__global__ void gather_init(const float* __restrict__ ut,
                            const float* __restrict__ gt,
                            const int*   __restrict__ ui,
                            const int*   __restrict__ pg,
                            const int*   __restrict__ ng,
                            float*       __restrict__ out) {
    int i = blockIdx.x * blockDim.x + threadIdx.x;    // B*D threads
    if (i >= B * D) return;
    int b = i >> 6, d = i & 63;
    float u = ut[(size_t)ui[b] * D + d];
    float p = gt[(size_t)pg[b] * D + d];
    float n = gt[(size_t)ng[b] * D + d];
    const int S = B * D;
    out[0 * S + i] = 0.25f * u;
    out[1 * S + i] = 0.25f * p;
    out[2 * S + i] = 0.25f * n;
    out[3 * S + i] = u;
    out[4 * S + i] = p;
    out[5 * S + i] = n;
}

// ---------------------------------------------------------------------------
// Per-level accumulation of 0.25 * emb_l (bf16) at the gathered rows
// ---------------------------------------------------------------------------
__global__ void gather_acc(const unsigned short* __restrict__ emb,
                           const int*   __restrict__ ui,
                           const int*   __restrict__ pg,
                           const int*   __restrict__ ng,
                           float*       __restrict__ out) {
    int i = blockIdx.x * blockDim.x + threadIdx.x;    // B*D threads
    if (i >= B * D) return;
    int b = i >> 6, d = i & 63;
    const int S = B * D;
    out[0 * S + i] += 0.25f * bf2f(emb[(size_t)ui[b] * D + d]);
    out[1 * S + i] += 0.25f * bf2f(emb[((size_t)NUM_USER + pg[b]) * D + d]);
    out[2 * S + i] += 0.25f * bf2f(emb[((size_t)NUM_USER + ng[b]) * D + d]);
}

// ---------------------------------------------------------------------------
extern "C" void kernel_launch(void* const* d_in, const int* in_sizes, int n_in,
                              void* d_out, int out_size, void* d_ws, size_t ws_size,
                              hipStream_t stream) {
    const float* ut   = (const float*)d_in[0];
    const float* gt   = (const float*)d_in[1];
    const float* vals = (const float*)d_in[2];
    const int*   rows = (const int*)d_in[3];
    const int*   cols = (const int*)d_in[4];
    const int*   ui   = (const int*)d_in[5];
    const int*   pg   = (const int*)d_in[6];
    const int*   ng   = (const int*)d_in[7];
    float* out = (float*)d_out;

    // --- workspace layout (bf16 embeddings: 32 MB each) ---
    char* ws = (char*)d_ws;
    unsigned short* emb0 = (unsigned short*)ws;  ws += (size_t)NN * D * sizeof(unsigned short);
    unsigned short* emb1 = (unsigned short*)ws;  ws += (size_t)NN * D * sizeof(unsigned short);
    unsigned short* emb2 = (unsigned short*)ws;  ws += (size_t)NN * D * sizeof(unsigned short);
    int2*  pairs   = (int2*)ws;    ws += (size_t)E_EDGES * sizeof(int2);   // 32 MB
    int2*  stage   = (int2*)ws;    ws += (size_t)E_EDGES * sizeof(int2);   // 32 MB
    int*   row_ptr = (int*)ws;     ws += (size_t)(NN + 1) * sizeof(int);
    int*   counts  = (int*)ws;     ws += (size_t)NN * sizeof(int);
    int*   blockSums = (int*)ws;   ws += (size_t)SCAN_BLOCKS * sizeof(int);
    int*   blockOffs = (int*)ws;   ws += (size_t)SCAN_BLOCKS * sizeof(int);
    int*   cursorA   = (int*)ws;   ws += (size_t)NB_BUCKETS * sizeof(int);

    // --- CSR build (once per call; reused for all 3 levels) ---
    hipMemsetAsync(counts, 0, (size_t)NN * sizeof(int), stream);
    hist_kernel<<<(E_EDGES + 255) / 256, 256, 0, stream>>>(rows, counts);
    scan_blocksums<<<SCAN_BLOCKS, 256, 0, stream>>>(counts, blockSums);
    scan_offsets<<<1, 256, 0, stream>>>(blockSums, blockOffs, row_ptr);
    scan_final<<<SCAN_BLOCKS, 256, 0, stream>>>(counts, blockOffs, row_ptr);
    init_bucket_cursors<<<1, 256, 0, stream>>>(row_ptr, cursorA);
    bucket_phaseA<<<(E_EDGES + CHUNK_EDGES - 1) / CHUNK_EDGES, 256, 0, stream>>>(
        rows, cols, vals, cursorA, stage);
    bucket_phaseB<<<NB_BUCKETS, PB_THREADS, 0, stream>>>(row_ptr, stage, pairs);

    // --- bf16 emb0 + outputs 3..5 + level-0 contribution ---
    {
        long long total4 = (long long)NN * D / 4;
        convert_tables<<<(int)((total4 + 255) / 256), 256, 0, stream>>>(ut, gt, emb0);
    }
    gather_init<<<(B * D + 255) / 256, 256, 0, stream>>>(ut, gt, ui, pg, ng, out);

    // --- propagation: 2 full levels (bf16) + output-sparse final level ---
    const int spmmBlocks = (NN + 3) / 4;   // 4 rows (waves) per 256-thread block
    spmm_pull_bf<<<spmmBlocks, 256, 0, stream>>>(row_ptr, pairs, emb0, emb1);
    gather_acc<<<(B * D + 255) / 256, 256, 0, stream>>>(emb1, ui, pg, ng, out);

    spmm_pull_bf<<<spmmBlocks, 256, 0, stream>>>(row_ptr, pairs, emb1, emb2);
    gather_acc<<<(B * D + 255) / 256, 256, 0, stream>>>(emb2, ui, pg, ng, out);

    // level 3: only the 24576 output rows, fused into the output accumulation
    final_pull<<<(3 * B + 3) / 4, 256, 0, stream>>>(row_ptr, pairs, emb2, ui, pg, ng, out);
}

// Round 2
// 514.158 us; speedup vs baseline: 1.4277x; 1.2386x over previous
//
#include <hip/hip_runtime.h>

#define NUM_USER  200000
#define NUM_GROUP 50000
#define NN        (NUM_USER + NUM_GROUP)   // 250000
#define E_EDGES   4000000
#define D         64
#define B         8192

#define BSHIFT       10                                     // 1024 rows / bucket
#define NB_BUCKETS   ((NN + (1 << BSHIFT) - 1) >> BSHIFT)   // 245
#define CHUNK_EDGES  4096                                   // edges per phase-A block
#define PB_THREADS   1024                                   // phase-B block size

// --- bf16 helpers (RNE; values are normal floats, no NaN path needed) ------
__device__ __forceinline__ float bf2f(unsigned short u) {
    return __uint_as_float(((unsigned int)u) << 16);
}
__device__ __forceinline__ unsigned short f2bf(float f) {
    unsigned int x = __float_as_uint(f);
    return (unsigned short)((x + 0x7FFFu + ((x >> 16) & 1u)) >> 16);
}
// packed-bf16 dword -> two floats (lo = even dim, hi = odd dim)
__device__ __forceinline__ float bflo(unsigned int u) { return __uint_as_float(u << 16); }
__device__ __forceinline__ float bfhi(unsigned int u) { return __uint_as_float(u & 0xFFFF0000u); }

// ---------------------------------------------------------------------------
// Convert concat(user_table, group_table) fp32 -> bf16 emb0 (vectorized x4)
// ---------------------------------------------------------------------------
__global__ void __launch_bounds__(256)
convert_tables(const float* __restrict__ ut,
               const float* __restrict__ gt,
               unsigned short* __restrict__ embT) {
    const long long total4 = (long long)NN * D / 4;
    const long long user4  = (long long)NUM_USER * D / 4;
    long long i = (long long)blockIdx.x * blockDim.x + threadIdx.x;
    if (i >= total4) return;
    float4 v = (i < user4) ? ((const float4*)ut)[i] : ((const float4*)gt)[i - user4];
    ushort4 o;
    o.x = f2bf(v.x); o.y = f2bf(v.y); o.z = f2bf(v.z); o.w = f2bf(v.w);
    ((ushort4*)embT)[i] = o;
}

// ---------------------------------------------------------------------------
// Bucket histogram: LDS-aggregated 245-counter histogram per 4096-edge block,
// then ONE global atomic per (block, nonempty bucket).  Replaces the 4M-way
// row-level atomic histogram (which was 125 MB of far-atomic HBM writes).
// ---------------------------------------------------------------------------
__global__ void __launch_bounds__(256)
bucket_hist(const int* __restrict__ rows, int* __restrict__ bucketCounts) {
    __shared__ int cnt[NB_BUCKETS];
    const int t = threadIdx.x;
    if (t < NB_BUCKETS) cnt[t] = 0;
    __syncthreads();
    const int base = blockIdx.x * CHUNK_EDGES;
    #pragma unroll
    for (int k = 0; k < CHUNK_EDGES / 256; ++k) {
        int e = base + t + k * 256;
        if (e < E_EDGES) atomicAdd(&cnt[rows[e] >> BSHIFT], 1);
    }
    __syncthreads();
    if (t < NB_BUCKETS && cnt[t] > 0) atomicAdd(&bucketCounts[t], cnt[t]);
}

// ---------------------------------------------------------------------------
// Scan of the 245 bucket counts (single small block):
//   bucketPtr[b] = exclusive prefix, bucketPtr[245] = E,
//   cursorA[b]   = staging cursor init,
//   row_ptr[NN]  = E (per-row entries are written by phase B).
// ---------------------------------------------------------------------------
__global__ void __launch_bounds__(256)
bucket_scan(const int* __restrict__ bucketCounts,
            int* __restrict__ bucketPtr,
            int* __restrict__ cursorA,
            int* __restrict__ row_ptr) {
    __shared__ int s[256];
    const int t = threadIdx.x;
    int v = (t < NB_BUCKETS) ? bucketCounts[t] : 0;
    s[t] = v;
    __syncthreads();
    for (int off = 1; off < 256; off <<= 1) {
        int u = (t >= off) ? s[t - off] : 0;
        __syncthreads();
        s[t] += u;
        __syncthreads();
    }
    int excl = s[t] - v;
    if (t < NB_BUCKETS) { bucketPtr[t] = excl; cursorA[t] = excl; }
    if (t == 255) {
        bucketPtr[NB_BUCKETS] = s[255];   // == E
        row_ptr[NN] = s[255];
    }
}

// ---------------------------------------------------------------------------
// Phase A: LDS-aggregated bucket append (parallel cursor reservation,
// 16-lane subgroup copy-out).
// Staged element: { (row_in_bucket << 18) | col, bits(val) }.
// ---------------------------------------------------------------------------
__global__ void __launch_bounds__(256)
bucket_phaseA(const int*   __restrict__ rows,
              const int*   __restrict__ cols,
              const float* __restrict__ vals,
              int*         __restrict__ cursorA,
              int2*        __restrict__ stage) {
    __shared__ int  cnt[256];
    __shared__ int  off[256];
    __shared__ int  cur[256];
    __shared__ int  gbase[256];
    __shared__ int2 stg[CHUNK_EDGES];    // 32 KB
    const int t = threadIdx.x;
    cnt[t] = 0;
    __syncthreads();

    const int base = blockIdx.x * CHUNK_EDGES;
    int re[CHUNK_EDGES / 256];           // cache rows -> no second global read
    #pragma unroll
    for (int k = 0; k < CHUNK_EDGES / 256; ++k) {
        int e = base + t + k * 256;
        re[k] = (e < E_EDGES) ? rows[e] : -1;
        if (re[k] >= 0) atomicAdd(&cnt[re[k] >> BSHIFT], 1);
    }
    __syncthreads();

    // exclusive scan of cnt -> off (Hillis-Steele over 256)
    int v = cnt[t];
    off[t] = v;
    __syncthreads();
    for (int o = 1; o < 256; o <<= 1) {
        int u = (t >= o) ? off[t - o] : 0;
        __syncthreads();
        off[t] += u;
        __syncthreads();
    }
    int excl = off[t] - v;
    __syncthreads();
    off[t] = excl;
    cur[t] = excl;
    // parallel cursor reservation: one independent atomic per bucket
    if (t < NB_BUCKETS && v > 0) gbase[t] = atomicAdd(&cursorA[t], v);
    __syncthreads();

    // place into LDS staging
    #pragma unroll
    for (int k = 0; k < CHUNK_EDGES / 256; ++k) {
        int r = re[k];
        if (r >= 0) {
            int e = base + t + k * 256;
            int b = r >> BSHIFT;
            int slot = atomicAdd(&cur[b], 1);
            stg[slot] = make_int2(((r & ((1 << BSHIFT) - 1)) << 18) | cols[e],
                                  __float_as_int(vals[e]));
        }
    }
    __syncthreads();

    // copy runs out: 16-lane subgroups (mean run length ~17), no atomics here
    const int sg = t >> 4;    // 0..15
    const int sl = t & 15;
    for (int b = sg; b < NB_BUCKETS; b += 16) {
        int n = cnt[b];
        if (n == 0) continue;
        int gb = gbase[b];
        int lb = off[b];
        for (int i = sl; i < n; i += 16)
            stage[gb + i] = stg[lb + i];
    }
}

// ---------------------------------------------------------------------------
// Phase B: ONE block (1024 threads) per bucket.
//   pass 1: LDS histogram of row-in-bucket over the bucket's staged edges
//   scan  : 1024-wide LDS exclusive scan -> exact row_ptr for this bucket
//   pass 2: exact CSR placement via LDS row cursors
// This is where per-row counts are derived -- no global row histogram needed.
// ---------------------------------------------------------------------------
__global__ void __launch_bounds__(PB_THREADS)
bucket_phaseB(const int*  __restrict__ bucketPtr,
              const int2* __restrict__ stage,
              int2*       __restrict__ pairs,
              int*        __restrict__ row_ptr) {
    __shared__ int cnt[1 << BSHIFT];     // per-row counts, then cursors
    __shared__ int scn[1 << BSHIFT];     // scan workspace
    const int b = blockIdx.x;
    const int rowBase = b << BSHIFT;
    const int nRows = (NN - rowBase < (1 << BSHIFT)) ? (NN - rowBase) : (1 << BSHIFT);
    const int t = threadIdx.x;
    cnt[t] = 0;
    __syncthreads();

    const int s = bucketPtr[b];
    const int e = bucketPtr[b + 1];

    // pass 1: count rows within bucket
    for (int i = s + t; i < e; i += PB_THREADS)
        atomicAdd(&cnt[stage[i].x >> 18], 1);
    __syncthreads();

    // exclusive scan over 1024 counts (Hillis-Steele, 10 steps)
    int v = cnt[t];
    scn[t] = v;
    __syncthreads();
    for (int o = 1; o < PB_THREADS; o <<= 1) {
        int u = (t >= o) ? scn[t - o] : 0;
        __syncthreads();
        scn[t] += u;
        __syncthreads();
    }
    int excl = scn[t] - v;

    // emit row_ptr for this bucket and init LDS cursors
    if (t < nRows) row_ptr[rowBase + t] = s + excl;
    __syncthreads();
    cnt[t] = s + excl;
    __syncthreads();

    // pass 2: exact placement
    for (int i = s + t; i < e; i += PB_THREADS) {
        int2 p = stage[i];
        int rib = p.x >> 18;
        int col = p.x & 0x3FFFF;
        int slot = atomicAdd(&cnt[rib], 1);
        pairs[slot] = make_int2(col, p.y);
    }
}

// ---------------------------------------------------------------------------
// Pull-mode SpMM over bf16 embeddings: one wave per destination row.
// Quarter-wave edge parallelism: 4 edges in flight, each handled by a
// 16-lane quarter; lane covers 4 dims via one 8-byte uint2 load.
// Unroll x2 -> 8 edges / 4 vmem instructions per wave-iteration.
// Cross-quarter reduction: 2x shfl_xor per row. fp32 acc, bf16 store.
// ---------------------------------------------------------------------------
__global__ void __launch_bounds__(256)
spmm_pull_bf(const int*  __restrict__ row_ptr,
             const int2* __restrict__ pairs,
             const unsigned short* __restrict__ x,
             unsigned short*       __restrict__ y) {
    const int row  = blockIdx.x * 4 + (threadIdx.x >> 6);   // 4 waves / block
    if (row >= NN) return;
    const int lane = threadIdx.x & 63;
    const int sub  = lane >> 4;          // quarter id 0..3 (edge slot)
    const int sl   = lane & 15;          // dims 4*sl .. 4*sl+3
    const int start = row_ptr[row];
    const int end   = row_ptr[row + 1];

    float a0 = 0.f, a1 = 0.f, a2 = 0.f, a3 = 0.f;
    int e = start + sub;                 // this quarter's edge ptr, stride 4
    for (; e + 4 < end; e += 8) {
        int2 p0 = pairs[e];
        int2 p1 = pairs[e + 4];
        uint2 u0 = *(const uint2*)(x + (unsigned)(p0.x * D + 4 * sl));
        uint2 u1 = *(const uint2*)(x + (unsigned)(p1.x * D + 4 * sl));
        float v0 = __int_as_float(p0.y);
        float v1 = __int_as_float(p1.y);
        a0 += v0 * bflo(u0.x); a1 += v0 * bfhi(u0.x);
        a2 += v0 * bflo(u0.y); a3 += v0 * bfhi(u0.y);
        a0 += v1 * bflo(u1.x); a1 += v1 * bfhi(u1.x);
        a2 += v1 * bflo(u1.y); a3 += v1 * bfhi(u1.y);
    }
    if (e < end) {                       // <=1 remaining edge per quarter
        int2 p = pairs[e];
        uint2 u = *(const uint2*)(x + (unsigned)(p.x * D + 4 * sl));
        float v = __int_as_float(p.y);
        a0 += v * bflo(u.x); a1 += v * bfhi(u.x);
        a2 += v * bflo(u.y); a3 += v * bfhi(u.y);
    }
    // combine the 4 quarters (same dims live at same sl in every quarter)
    a0 += __shfl_xor(a0, 16); a0 += __shfl_xor(a0, 32);
    a1 += __shfl_xor(a1, 16); a1 += __shfl_xor(a1, 32);
    a2 += __shfl_xor(a2, 16); a2 += __shfl_xor(a2, 32);
    a3 += __shfl_xor(a3, 16); a3 += __shfl_xor(a3, 32);
    if (sub == 0) {
        ushort4 o;
        o.x = f2bf(a0); o.y = f2bf(a1); o.z = f2bf(a2); o.w = f2bf(a3);
        *(ushort4*)(y + (unsigned)(row * D + 4 * sl)) = o;
    }
}

// ---------------------------------------------------------------------------
// Final level, output-sparse: one wave per OUTPUT SLOT (3*B slots), same
// quarter-wave structure as spmm_pull_bf; adds 0.25*sum into d_out.
// ---------------------------------------------------------------------------
__global__ void __launch_bounds__(256)
final_pull(const int*  __restrict__ row_ptr,
           const int2* __restrict__ pairs,
           const unsigned short* __restrict__ x,      // emb2 bf16
           const int*  __restrict__ ui,
           const int*  __restrict__ pg,
           const int*  __restrict__ ng,
           float*      __restrict__ out) {
    const int slot = blockIdx.x * 4 + (threadIdx.x >> 6);   // 0 .. 3*B-1
    if (slot >= 3 * B) return;
    const int lane = threadIdx.x & 63;
    const int sub  = lane >> 4;
    const int sl   = lane & 15;
    const int region = slot / B;                 // 0=user, 1=pos, 2=neg
    const int b      = slot - region * B;
    int row;
    if (region == 0)      row = ui[b];
    else if (region == 1) row = NUM_USER + pg[b];
    else                  row = NUM_USER + ng[b];

    const int start = row_ptr[row];
    const int end   = row_ptr[row + 1];
    float a0 = 0.f, a1 = 0.f, a2 = 0.f, a3 = 0.f;
    int e = start + sub;
    for (; e + 4 < end; e += 8) {
        int2 p0 = pairs[e];
        int2 p1 = pairs[e + 4];
        uint2 u0 = *(const uint2*)(x + (unsigned)(p0.x * D + 4 * sl));
        uint2 u1 = *(const uint2*)(x + (unsigned)(p1.x * D + 4 * sl));
        float v0 = __int_as_float(p0.y);
        float v1 = __int_as_float(p1.y);
        a0 += v0 * bflo(u0.x); a1 += v0 * bfhi(u0.x);
        a2 += v0 * bflo(u0.y); a3 += v0 * bfhi(u0.y);
        a0 += v1 * bflo(u1.x); a1 += v1 * bfhi(u1.x);
        a2 += v1 * bflo(u1.y); a3 += v1 * bfhi(u1.y);
    }
    if (e < end) {
        int2 p = pairs[e];
        uint2 u = *(const uint2*)(x + (unsigned)(p.x * D + 4 * sl));
        float v = __int_as_float(p.y);
        a0 += v * bflo(u.x); a1 += v * bfhi(u.x);
        a2 += v * bflo(u.y); a3 += v * bfhi(u.y);
    }
    a0 += __shfl_xor(a0, 16); a0 += __shfl_xor(a0, 32);
    a1 += __shfl_xor(a1, 16); a1 += __shfl_xor(a1, 32);
    a2 += __shfl_xor(a2, 16); a2 += __shfl_xor(a2, 32);
    a3 += __shfl_xor(a3, 16); a3 += __shfl_xor(a3, 32);
    if (sub == 0) {
        float* o = out + (unsigned)(region * B * D + b * D + 4 * sl);
        float4 t = *(float4*)o;
        t.x += 0.25f * a0; t.y += 0.25f * a1;
        t.z += 0.25f * a2; t.w += 0.25f * a3;
        *(float4*)o = t;
    }
}

// ---------------------------------------------------------------------------
// Output init: raw table gathers (outputs 3..5, exact fp32) and the level-0
// contribution (0.25 * table rows) into outputs 0..2.
// ---------------------------------------------------------------------------
__global__ void gather_init(const float* __restrict__ ut,
                            const float* __restrict__ gt,
                            const int*   __restrict__ ui,
                            const int*   __restrict__ pg,
                            const int*   __restrict__ ng,
                            float*       __restrict__ out) {
    int i = blockIdx.x * blockDim.x + threadIdx.x;    // B*D threads
    if (i >= B * D) return;
    int b = i >> 6, d = i & 63;
    float u = ut[(size_t)ui[b] * D + d];
    float p = gt[(size_t)pg[b] * D + d];
    float n = gt[(size_t)ng[b] * D + d];
    const int S = B * D;
    out[0 * S + i] = 0.25f * u;
    out[1 * S + i] = 0.25f * p;
    out[2 * S + i] = 0.25f * n;
    out[3 * S + i] = u;
    out[4 * S + i] = p;
    out[5 * S + i] = n;
}

// ---------------------------------------------------------------------------
// Per-level accumulation of 0.25 * emb_l (bf16) at the gathered rows
// ---------------------------------------------------------------------------
__global__ void gather_acc(const unsigned short* __restrict__ emb,
                           const int*   __restrict__ ui,
                           const int*   __restrict__ pg,
                           const int*   __restrict__ ng,
                           float*       __restrict__ out) {
    int i = blockIdx.x * blockDim.x + threadIdx.x;    // B*D threads
    if (i >= B * D) return;
    int b = i >> 6, d = i & 63;
    const int S = B * D;
    out[0 * S + i] += 0.25f * bf2f(emb[(size_t)ui[b] * D + d]);
    out[1 * S + i] += 0.25f * bf2f(emb[((size_t)NUM_USER + pg[b]) * D + d]);
    out[2 * S + i] += 0.25f * bf2f(emb[((size_t)NUM_USER + ng[b]) * D + d]);
}

// ---------------------------------------------------------------------------
extern "C" void kernel_launch(void* const* d_in, const int* in_sizes, int n_in,
                              void* d_out, int out_size, void* d_ws, size_t ws_size,
                              hipStream_t stream) {
    const float* ut   = (const float*)d_in[0];
    const float* gt   = (const float*)d_in[1];
    const float* vals = (const float*)d_in[2];
    const int*   rows = (const int*)d_in[3];
    const int*   cols = (const int*)d_in[4];
    const int*   ui   = (const int*)d_in[5];
    const int*   pg   = (const int*)d_in[6];
    const int*   ng   = (const int*)d_in[7];
    float* out = (float*)d_out;

    // --- workspace layout (bf16 embeddings: 32 MB each) ---
    char* ws = (char*)d_ws;
    unsigned short* emb0 = (unsigned short*)ws;  ws += (size_t)NN * D * sizeof(unsigned short);
    unsigned short* emb1 = (unsigned short*)ws;  ws += (size_t)NN * D * sizeof(unsigned short);
    unsigned short* emb2 = (unsigned short*)ws;  ws += (size_t)NN * D * sizeof(unsigned short);
    int2*  pairs   = (int2*)ws;    ws += (size_t)E_EDGES * sizeof(int2);   // 32 MB
    int2*  stage   = (int2*)ws;    ws += (size_t)E_EDGES * sizeof(int2);   // 32 MB
    int*   row_ptr = (int*)ws;     ws += (size_t)(NN + 1) * sizeof(int);
    int*   bucketCounts = (int*)ws; ws += (size_t)NB_BUCKETS * sizeof(int);
    int*   bucketPtr    = (int*)ws; ws += (size_t)(NB_BUCKETS + 1) * sizeof(int);
    int*   cursorA      = (int*)ws; ws += (size_t)NB_BUCKETS * sizeof(int);

    // --- CSR build (once per call; reused for all 3 levels) ---
    hipMemsetAsync(bucketCounts, 0, (size_t)NB_BUCKETS * sizeof(int), stream);
    bucket_hist<<<(E_EDGES + CHUNK_EDGES - 1) / CHUNK_EDGES, 256, 0, stream>>>(rows, bucketCounts);
    bucket_scan<<<1, 256, 0, stream>>>(bucketCounts, bucketPtr, cursorA, row_ptr);
    bucket_phaseA<<<(E_EDGES + CHUNK_EDGES - 1) / CHUNK_EDGES, 256, 0, stream>>>(
        rows, cols, vals, cursorA, stage);
    bucket_phaseB<<<NB_BUCKETS, PB_THREADS, 0, stream>>>(bucketPtr, stage, pairs, row_ptr);

    // --- bf16 emb0 + outputs 3..5 + level-0 contribution ---
    {
        long long total4 = (long long)NN * D / 4;
        convert_tables<<<(int)((total4 + 255) / 256), 256, 0, stream>>>(ut, gt, emb0);
    }
    gather_init<<<(B * D + 255) / 256, 256, 0, stream>>>(ut, gt, ui, pg, ng, out);

    // --- propagation: 2 full levels (bf16) + output-sparse final level ---
    const int spmmBlocks = (NN + 3) / 4;   // 4 rows (waves) per 256-thread block
    spmm_pull_bf<<<spmmBlocks, 256, 0, stream>>>(row_ptr, pairs, emb0, emb1);
    gather_acc<<<(B * D + 255) / 256, 256, 0, stream>>>(emb1, ui, pg, ng, out);

    spmm_pull_bf<<<spmmBlocks, 256, 0, stream>>>(row_ptr, pairs, emb1, emb2);
    gather_acc<<<(B * D + 255) / 256, 256, 0, stream>>>(emb2, ui, pg, ng, out);

    // level 3: only the 24576 output rows, fused into the output accumulation
    final_pull<<<(3 * B + 3) / 4, 256, 0, stream>>>(row_ptr, pairs, emb2, ui, pg, ng, out);
}